// Round 3
// baseline (399072.046 us; speedup 1.0000x reference)
//
#include <hip/hip_runtime.h>
#include <hip/hip_fp16.h>

typedef _Float16 half8 __attribute__((ext_vector_type(8)));
typedef float floatx4 __attribute__((ext_vector_type(4)));
typedef unsigned int uint4v __attribute__((ext_vector_type(4)));

#define INPUT  512
#define HIDDEN 1024
#define OUTPUT 256
#define BATCH  128
#define SEQ    512

// ---------------------------------------------------------------------------
// K0: transpose + fp32->fp16 convert:  in [K][N] f32  ->  out [N][K] f16
// ---------------------------------------------------------------------------
__global__ __launch_bounds__(256) void transpose_f32_to_f16(
    const float* __restrict__ in, _Float16* __restrict__ out, int K, int N) {
  __shared__ float tile[32][33];
  int bi = blockIdx.x;
  int bj = blockIdx.y;
  int cc = threadIdx.x & 31;
  int rr = threadIdx.x >> 5;
#pragma unroll
  for (int s = 0; s < 4; ++s) {
    int r = rr + 8 * s;
    tile[r][cc] = in[(size_t)(bi * 32 + r) * N + bj * 32 + cc];
  }
  __syncthreads();
#pragma unroll
  for (int s = 0; s < 4; ++s) {
    int nl = rr + 8 * s;
    out[(size_t)(bj * 32 + nl) * K + bi * 32 + cc] = (_Float16)tile[cc][nl];
  }
}

// ---------------------------------------------------------------------------
// K1: xin[S][B][H] = x @ W_in  (time-major so the recurrence reads 256KB/step)
// ---------------------------------------------------------------------------
__global__ __launch_bounds__(256) void xin_gemm(
    const float* __restrict__ x, const _Float16* __restrict__ WinT,
    _Float16* __restrict__ xin) {
  int bid = blockIdx.x;
  int bn = bid & 15;
  int bm = bid >> 4;
  int tid = threadIdx.x;
  int l = tid & 63;
  int w = tid >> 6;
  int l15 = l & 15;
  int lk = (l >> 4) << 3;

  int rowbase = bm * 64 + w * 16;
  int colbase = bn * 64;

  floatx4 acc[4];
#pragma unroll
  for (int nt = 0; nt < 4; ++nt) acc[nt] = (floatx4){0.f, 0.f, 0.f, 0.f};

  int arow = rowbase + l15;
  const float* xrow = x + (size_t)arow * INPUT;

  for (int k0 = 0; k0 < INPUT; k0 += 32) {
    int ak = k0 + lk;
    float4 xa = *reinterpret_cast<const float4*>(xrow + ak);
    float4 xb = *reinterpret_cast<const float4*>(xrow + ak + 4);
    half8 a;
    a[0] = (_Float16)xa.x; a[1] = (_Float16)xa.y;
    a[2] = (_Float16)xa.z; a[3] = (_Float16)xa.w;
    a[4] = (_Float16)xb.x; a[5] = (_Float16)xb.y;
    a[6] = (_Float16)xb.z; a[7] = (_Float16)xb.w;
#pragma unroll
    for (int nt = 0; nt < 4; ++nt) {
      int bcol = colbase + nt * 16 + l15;
      half8 b = *reinterpret_cast<const half8*>(WinT + (size_t)bcol * INPUT + ak);
      acc[nt] = __builtin_amdgcn_mfma_f32_16x16x32_f16(a, b, acc[nt], 0, 0, 0);
    }
  }

  int orow = rowbase + ((l >> 4) << 2);
#pragma unroll
  for (int nt = 0; nt < 4; ++nt)
#pragma unroll
    for (int i = 0; i < 4; ++i) {
      int r = orow + i;
      int b = r >> 9;
      int s = r & 511;
      xin[((size_t)s * BATCH + b) * HIDDEN + colbase + nt * 16 + l15] =
          (_Float16)acc[nt][i];
    }
}

// ---------------------------------------------------------------------------
// K2: persistent recurrence; tagged-word exchange, XCD-local fast path.
// hbuf u64 layout: [2 banks][8 grp][512 tid][16 row] — each consumer thread's
// poll set is one contiguous 128B run -> 8x dwordx4 in a single asm block.
// word = (fp16(h)<<16) | step_tag.
// Fast path (runtime-verified same-XCD group): plain stores + sc0 loads (L2-
// coherent within an XCD). Slow path / escape hatch: agent-scope atomics.
// ---------------------------------------------------------------------------
__global__ __launch_bounds__(512, 1) void liquid_scan(
    const _Float16* __restrict__ xin,   // [S][B][H]
    const _Float16* __restrict__ WhT,   // [H n][H k]
    const float* __restrict__ b_in, const float* __restrict__ b_h,
    const float* __restrict__ tau,
    unsigned int* hbuf,                 // 2*65536 u64, memset-0
    float* __restrict__ hfinal,         // [B][H] f32
    unsigned int* meta) {               // [128], memset-0
  int blk = blockIdx.x;
  int m = blk & 7;
  int j = blk >> 3;
  int tid = threadIdx.x;
  int l = tid & 63;
  int w = tid >> 6;
  int nt = w & 3;
  int kg = w >> 2;
  int l15 = l & 15;
  int lk = (l >> 4) << 3;

  __shared__ _Float16 Ald[16][1032];
  __shared__ float part[4][4][64];
  __shared__ unsigned int mt[128];

  // ---- startup handshake: discover XCD placement, pick exchange path ----
  int xcd;
  asm volatile("s_getreg_b32 %0, hwreg(HW_REG_XCC_ID)" : "=s"(xcd));
  if (tid == 0)
    __hip_atomic_store(&meta[blk], (unsigned)xcd + 1u, __ATOMIC_RELAXED,
                       __HIP_MEMORY_SCOPE_AGENT);
  if (tid < 128) {
    unsigned v;
    do {
      v = __hip_atomic_load(&meta[tid], __ATOMIC_RELAXED,
                            __HIP_MEMORY_SCOPE_AGENT);
    } while (v == 0u);
    mt[tid] = v;
  }
  __syncthreads();
  unsigned gmin = 0xffffffffu, gmax = 0u, mmin = 0xffffffffu, mmax = 0u;
  for (int i = 0; i < 128; ++i) {
    unsigned v = mt[i];
    gmin = v < gmin ? v : gmin;
    gmax = v > gmax ? v : gmax;
    if ((i & 7) == m) {
      mmin = v < mmin ? v : mmin;
      mmax = v > mmax ? v : mmax;
    }
  }
  // fast iff my group is on one XCD AND the table shows real diversity
  // (1 block/CU forced via LDS padding => 128 blocks span >=4 XCDs, so a
  //  globally-uniform table can only mean a bogus register read).
  const bool fastp = (mmin == mmax) && (gmin != gmax);

  // ---- weight fragments (stationary in VGPRs) ----
  int ncol = j * 64 + nt * 16 + l15;
  half8 bfrag[16];
  const _Float16* wbase = WhT + (size_t)ncol * HIDDEN + kg * 512 + lk;
#pragma unroll
  for (int q = 0; q < 16; ++q)
    bfrag[q] = *reinterpret_cast<const half8*>(wbase + q * 32);

  float bias_c = 0.f, invtau_c = 1.f;
  if (kg == 0) {
    bias_c = b_in[ncol] + b_h[ncol];
    invtau_c = 1.0f / tau[ncol];
  }
  float hown[4] = {0.f, 0.f, 0.f, 0.f};
  int erow_i = (l >> 4) << 2;              // local row base (0..12)
  int erow0 = m * 16 + erow_i;             // global batch row base

  unsigned long long* hb64 = (unsigned long long*)hbuf;
  const size_t pbase = (size_t)m * 8192 + (size_t)tid * 16;  // u64 units

  for (int t = 0; t < SEQ; ++t) {
    // xin prefetch — independent of h_t, issued before the poll
    float xv[4];
    if (kg == 0) {
#pragma unroll
      for (int i = 0; i < 4; ++i)
        xv[i] = (float)xin[((size_t)t * BATCH + erow0 + i) * HIDDEN + ncol];
    }

    if (t > 0) {
      unsigned long long* bp = hb64 + (size_t)(t & 1) * 65536 + pbase;
      uint4v q0, q1, q2, q3, q4, q5, q6, q7;
      const unsigned want = (unsigned)t;
      int spins = 0;
      for (;;) {
        if (fastp && spins < 1024) {
          asm volatile(
              "global_load_dwordx4 %0, %8, off sc0\n\t"
              "global_load_dwordx4 %1, %8, off offset:16 sc0\n\t"
              "global_load_dwordx4 %2, %8, off offset:32 sc0\n\t"
              "global_load_dwordx4 %3, %8, off offset:48 sc0\n\t"
              "global_load_dwordx4 %4, %8, off offset:64 sc0\n\t"
              "global_load_dwordx4 %5, %8, off offset:80 sc0\n\t"
              "global_load_dwordx4 %6, %8, off offset:96 sc0\n\t"
              "global_load_dwordx4 %7, %8, off offset:112 sc0\n\t"
              "s_waitcnt vmcnt(0)"
              : "=v"(q0), "=v"(q1), "=v"(q2), "=v"(q3),
                "=v"(q4), "=v"(q5), "=v"(q6), "=v"(q7)
              : "v"(bp)
              : "memory");
        } else {
          unsigned long long vv[16];
#pragma unroll
          for (int i = 0; i < 16; ++i)
            vv[i] = __hip_atomic_load(bp + i, __ATOMIC_RELAXED,
                                      __HIP_MEMORY_SCOPE_AGENT);
          q0 = (uint4v){(unsigned)vv[0], (unsigned)(vv[0] >> 32), (unsigned)vv[1], (unsigned)(vv[1] >> 32)};
          q1 = (uint4v){(unsigned)vv[2], (unsigned)(vv[2] >> 32), (unsigned)vv[3], (unsigned)(vv[3] >> 32)};
          q2 = (uint4v){(unsigned)vv[4], (unsigned)(vv[4] >> 32), (unsigned)vv[5], (unsigned)(vv[5] >> 32)};
          q3 = (uint4v){(unsigned)vv[6], (unsigned)(vv[6] >> 32), (unsigned)vv[7], (unsigned)(vv[7] >> 32)};
          q4 = (uint4v){(unsigned)vv[8], (unsigned)(vv[8] >> 32), (unsigned)vv[9], (unsigned)(vv[9] >> 32)};
          q5 = (uint4v){(unsigned)vv[10], (unsigned)(vv[10] >> 32), (unsigned)vv[11], (unsigned)(vv[11] >> 32)};
          q6 = (uint4v){(unsigned)vv[12], (unsigned)(vv[12] >> 32), (unsigned)vv[13], (unsigned)(vv[13] >> 32)};
          q7 = (uint4v){(unsigned)vv[14], (unsigned)(vv[14] >> 32), (unsigned)vv[15], (unsigned)(vv[15] >> 32)};
        }
        unsigned bad = 0;
#pragma unroll
        for (int i = 0; i < 4; ++i) {
          bad |= (q0[i] ^ want) & 0xFFFFu; bad |= (q1[i] ^ want) & 0xFFFFu;
          bad |= (q2[i] ^ want) & 0xFFFFu; bad |= (q3[i] ^ want) & 0xFFFFu;
          bad |= (q4[i] ^ want) & 0xFFFFu; bad |= (q5[i] ^ want) & 0xFFFFu;
          bad |= (q6[i] ^ want) & 0xFFFFu; bad |= (q7[i] ^ want) & 0xFFFFu;
        }
        if (!bad) break;
        ++spins;
      }
      // strip tags: u64 pair (rows 2k,2k+1) -> packed fp16 pair per row
      unsigned c = 2 * tid;
#define STRIP(Q, R)                                                          \
  *reinterpret_cast<unsigned int*>(&Ald[(R)][c]) =                           \
      __builtin_amdgcn_perm(Q[1], Q[0], 0x07060302u);                        \
  *reinterpret_cast<unsigned int*>(&Ald[(R) + 1][c]) =                       \
      __builtin_amdgcn_perm(Q[3], Q[2], 0x07060302u);
      STRIP(q0, 0) STRIP(q1, 2) STRIP(q2, 4) STRIP(q3, 6)
      STRIP(q4, 8) STRIP(q5, 10) STRIP(q6, 12) STRIP(q7, 14)
#undef STRIP
    }
    __syncthreads();  // B1: h_t staged

    floatx4 acc = (floatx4){0.f, 0.f, 0.f, 0.f};
    if (t > 0) {
      const int kb = kg * 512 + lk;
#pragma unroll
      for (int q = 0; q < 16; ++q) {
        half8 a = *reinterpret_cast<const half8*>(&Ald[l15][kb + q * 32]);
        acc = __builtin_amdgcn_mfma_f32_16x16x32_f16(a, bfrag[q], acc, 0, 0, 0);
      }
    }
    if (kg == 1) {
#pragma unroll
      for (int i = 0; i < 4; ++i) part[nt][i][l] = acc[i];
    }
    __syncthreads();  // B2: partials ready; protects Ald WAR

    if (kg == 0) {
      const size_t bankw = (size_t)((t + 1) & 1) * 131072;  // u32 units
#pragma unroll
      for (int i = 0; i < 4; ++i) {
        float pre = acc[i] + part[nt][i][l] + xv[i] + bias_c;
        float xc = fminf(fmaxf(pre, -15.f), 15.f);
        float e = __expf(2.f * xc);
        float dx = (e - 1.f) / (e + 1.f);
        float hn = hown[i] + (dx - hown[i]) * invtau_c;
        hown[i] = hn;
        if (t < SEQ - 1) {
          unsigned short hb16 = __builtin_bit_cast(unsigned short, (_Float16)hn);
          unsigned word = ((unsigned)hb16 << 16) | (unsigned)(t + 1);
          size_t idx = bankw +
                       (((size_t)m * 8192 + (size_t)(ncol >> 1) * 16 +
                         (erow_i + i)) << 1) + (ncol & 1);
          unsigned int* p = hbuf + idx;
          if (fastp) {
            asm volatile("global_store_dword %0, %1, off" ::"v"(p), "v"(word)
                         : "memory");
          } else {
            __hip_atomic_store(p, word, __ATOMIC_RELAXED,
                               __HIP_MEMORY_SCOPE_AGENT);
          }
        } else {
          hfinal[(size_t)(erow0 + i) * HIDDEN + ncol] = hn;
        }
      }
    }
  }
}

// ---------------------------------------------------------------------------
// K3: out[B][256] = hfinal @ W_out + b_out
// ---------------------------------------------------------------------------
__global__ __launch_bounds__(256) void out_gemm(
    const float* __restrict__ hfinal, const float* __restrict__ Wout,
    const float* __restrict__ bout, float* __restrict__ out) {
  int b0 = blockIdx.x * 2;
  int o = threadIdx.x;
  float a0 = 0.f, a1 = 0.f;
  for (int k = 0; k < HIDDEN; ++k) {
    float wv = Wout[(size_t)k * OUTPUT + o];
    a0 += hfinal[(size_t)b0 * HIDDEN + k] * wv;
    a1 += hfinal[(size_t)(b0 + 1) * HIDDEN + k] * wv;
  }
  out[(size_t)b0 * OUTPUT + o] = a0 + bout[o];
  out[(size_t)(b0 + 1) * OUTPUT + o] = a1 + bout[o];
}

// ---------------------------------------------------------------------------
extern "C" void kernel_launch(void* const* d_in, const int* in_sizes, int n_in,
                              void* d_out, int out_size, void* d_ws,
                              size_t ws_size, hipStream_t stream) {
  const float* x     = (const float*)d_in[0];
  const float* W_in  = (const float*)d_in[1];
  const float* b_in  = (const float*)d_in[2];
  const float* W_h   = (const float*)d_in[3];
  const float* b_h   = (const float*)d_in[4];
  const float* tau   = (const float*)d_in[5];
  const float* W_out = (const float*)d_in[6];
  const float* b_out = (const float*)d_in[7];
  float* out = (float*)d_out;

  char* ws = (char*)d_ws;
  _Float16* xin = (_Float16*)ws;  ws += (size_t)BATCH * SEQ * HIDDEN * 2;  // 134MB
  _Float16* WinT = (_Float16*)ws; ws += (size_t)HIDDEN * INPUT * 2;        // 1MB
  _Float16* WhT = (_Float16*)ws;  ws += (size_t)HIDDEN * HIDDEN * 2;       // 2MB
  unsigned int* hbuf = (unsigned int*)ws;
  ws += (size_t)2 * BATCH * HIDDEN * 4;                                    // 1MB
  float* hfin = (float*)ws;       ws += (size_t)BATCH * HIDDEN * 4;        // 512KB
  unsigned int* meta = (unsigned int*)ws; ws += 128 * 4;

  hipMemsetAsync(hbuf, 0, (size_t)2 * BATCH * HIDDEN * 4, stream);
  hipMemsetAsync(meta, 0, 128 * 4, stream);

  transpose_f32_to_f16<<<dim3(INPUT / 32, HIDDEN / 32), 256, 0, stream>>>(
      W_in, WinT, INPUT, HIDDEN);
  transpose_f32_to_f16<<<dim3(HIDDEN / 32, HIDDEN / 32), 256, 0, stream>>>(
      W_h, WhT, HIDDEN, HIDDEN);

  xin_gemm<<<(BATCH * SEQ / 64) * (HIDDEN / 64), 256, 0, stream>>>(x, WinT, xin);

  // 48KB dynamic LDS pads per-block LDS to ~86KB -> exactly 1 block/CU,
  // which the handshake's diversity guard relies on.
  liquid_scan<<<128, 512, 49152, stream>>>(xin, WhT, b_in, b_h, tau, hbuf,
                                           hfin, meta);

  out_gemm<<<BATCH / 2, OUTPUT, 0, stream>>>(hfin, W_out, b_out, out);
}

// Round 4
// 2571.814 us; speedup vs baseline: 155.1714x; 155.1714x over previous
//
#include <hip/hip_runtime.h>
#include <hip/hip_fp16.h>

typedef _Float16 half8 __attribute__((ext_vector_type(8)));
typedef float floatx4 __attribute__((ext_vector_type(4)));
typedef unsigned int uintx4 __attribute__((ext_vector_type(4)));

#define INPUT  512
#define HIDDEN 1024
#define OUTPUT 256
#define BATCH  128
#define SEQ    512

// ---------------------------------------------------------------------------
// K0: transpose + fp32->fp16 convert:  in [K][N] f32  ->  out [N][K] f16
// ---------------------------------------------------------------------------
__global__ __launch_bounds__(256) void transpose_f32_to_f16(
    const float* __restrict__ in, _Float16* __restrict__ out, int K, int N) {
  __shared__ float tile[32][33];
  int bi = blockIdx.x;
  int bj = blockIdx.y;
  int cc = threadIdx.x & 31;
  int rr = threadIdx.x >> 5;
#pragma unroll
  for (int s = 0; s < 4; ++s) {
    int r = rr + 8 * s;
    tile[r][cc] = in[(size_t)(bi * 32 + r) * N + bj * 32 + cc];
  }
  __syncthreads();
#pragma unroll
  for (int s = 0; s < 4; ++s) {
    int nl = rr + 8 * s;
    out[(size_t)(bj * 32 + nl) * K + bi * 32 + cc] = (_Float16)tile[cc][nl];
  }
}

// ---------------------------------------------------------------------------
// K1: xin[S][B][H] = x @ W_in.  Block swizzle: XCD x (= bid%8, round-robin
// dispatch heuristic) owns batch-rows slice [x*8192, (x+1)*8192) so each x
// tile is fetched from HBM once and served from that XCD's L2 to all 16
// N-blocks (perf-only assumption; correctness is independent of placement).
// ---------------------------------------------------------------------------
__global__ __launch_bounds__(256) void xin_gemm(
    const float* __restrict__ x, const _Float16* __restrict__ WinT,
    _Float16* __restrict__ xin) {
  int bid = blockIdx.x;
  int bm = (bid & 7) * 128 + (bid >> 7);   // 0..1023
  int bn = (bid >> 3) & 15;                // 0..15
  int tid = threadIdx.x;
  int l = tid & 63;
  int w = tid >> 6;
  int l15 = l & 15;
  int lk = (l >> 4) << 3;

  int rowbase = bm * 64 + w * 16;
  int colbase = bn * 64;

  floatx4 acc[4];
#pragma unroll
  for (int nt = 0; nt < 4; ++nt) acc[nt] = (floatx4){0.f, 0.f, 0.f, 0.f};

  int arow = rowbase + l15;
  const float* xrow = x + (size_t)arow * INPUT;

  for (int k0 = 0; k0 < INPUT; k0 += 32) {
    int ak = k0 + lk;
    float4 xa = *reinterpret_cast<const float4*>(xrow + ak);
    float4 xb = *reinterpret_cast<const float4*>(xrow + ak + 4);
    half8 a;
    a[0] = (_Float16)xa.x; a[1] = (_Float16)xa.y;
    a[2] = (_Float16)xa.z; a[3] = (_Float16)xa.w;
    a[4] = (_Float16)xb.x; a[5] = (_Float16)xb.y;
    a[6] = (_Float16)xb.z; a[7] = (_Float16)xb.w;
#pragma unroll
    for (int nt = 0; nt < 4; ++nt) {
      int bcol = colbase + nt * 16 + l15;
      half8 b = *reinterpret_cast<const half8*>(WinT + (size_t)bcol * INPUT + ak);
      acc[nt] = __builtin_amdgcn_mfma_f32_16x16x32_f16(a, b, acc[nt], 0, 0, 0);
    }
  }

  int orow = rowbase + ((l >> 4) << 2);
#pragma unroll
  for (int nt = 0; nt < 4; ++nt)
#pragma unroll
    for (int i = 0; i < 4; ++i) {
      int r = orow + i;
      int b = r >> 9;
      int s = r & 511;
      xin[((size_t)s * BATCH + b) * HIDDEN + colbase + nt * 16 + l15] =
          (_Float16)acc[nt][i];
    }
}

// ---------------------------------------------------------------------------
// K2: persistent recurrence, tagged-word exchange (R2 semantics: agent-scope
// relaxed atomics / sc1 — write-through to coherent point, proven correct).
// hbuf per (bank,group): plain row-major [16 rows][1024 cols] of tagged u32
// (payload fp16 in hi16, step tag in lo16).  Thread t polls words 4t..4t+3
// of each 2-row chunk i: one global_load_dwordx4 per (wave,i) covers 1KB
// CONTIGUOUS -> full line utilization (R2 wasted 8x on scattered polls).
// Selective re-poll: only slabs whose wave-ballot shows a stale tag.
// ---------------------------------------------------------------------------
__global__ __launch_bounds__(512, 1) void liquid_scan(
    const _Float16* __restrict__ xin,   // [S][B][H]
    const _Float16* __restrict__ WhT,   // [H n][H k]
    const float* __restrict__ b_in, const float* __restrict__ b_h,
    const float* __restrict__ tau,
    unsigned int* hbuf,                 // [2][8][16384] tagged u32
    float* __restrict__ hfinal) {       // [B][H] f32
  int blk = blockIdx.x;
  int m = blk & 7;                  // batch group (16 rows)
  int j = blk >> 3;                 // N slice (64 cols)
  int tid = threadIdx.x;
  int l = tid & 63;
  int w = tid >> 6;
  int nt = w & 3;
  int kg = w >> 2;
  int l15 = l & 15;
  int lk = (l >> 4) << 3;

  __shared__ _Float16 Ald[16][1032];   // padded: MFMA b128 reads 2-way (free)
  __shared__ float part[4][4][64];     // [nt][i][lane] — conflict-free

  // W_h slice stationary in VGPRs (16 ktiles of 32)
  int ncol = j * 64 + nt * 16 + l15;
  half8 bfrag[16];
  const _Float16* wbase = WhT + (size_t)ncol * HIDDEN + kg * 512 + lk;
#pragma unroll
  for (int q = 0; q < 16; ++q)
    bfrag[q] = *reinterpret_cast<const half8*>(wbase + q * 32);

  float bias_c = 0.f, invtau_c = 1.f;
  if (kg == 0) {
    bias_c = b_in[ncol] + b_h[ncol];
    invtau_c = 1.0f / tau[ncol];
  }
  float hown[4] = {0.f, 0.f, 0.f, 0.f};
  int erow_i = (l >> 4) << 2;              // local row base (0,4,8,12)
  int erow0 = m * 16 + erow_i;             // global batch row base

  // poll/strip assignment: word p = i*2048 + 4*tid + e  <->  row = 2i+(tid>>8),
  // col = 4*(tid&255)+e   (identity layout: p = row*1024 + col)
  const int srow = tid >> 8;
  const int scol4 = (tid & 255) * 4;
  unsigned int* gbase = hbuf + m * 16384 + tid * 4;

  for (int t = 0; t < SEQ; ++t) {
    // xin prefetch — independent of h_t, issued before the poll
    float xv[4];
    if (kg == 0) {
#pragma unroll
      for (int i = 0; i < 4; ++i)
        xv[i] = (float)xin[((size_t)t * BATCH + erow0 + i) * HIDDEN + ncol];
    }

    if (t > 0) {
      unsigned int* bp = gbase + (size_t)(t & 1) * 131072;
      const unsigned want = (unsigned)t;
      uintx4 q0, q1, q2, q3, q4, q5, q6, q7;
      unsigned need = 255u;
      do {
#define ISSUE(Q, I)                                                       \
        if (need & (1u << I))                                             \
          asm volatile("global_load_dwordx4 %0, %1, off sc1"              \
                       : "=v"(Q) : "v"(bp + I * 2048) : "memory");
        ISSUE(q0, 0) ISSUE(q1, 1) ISSUE(q2, 2) ISSUE(q3, 3)
        ISSUE(q4, 4) ISSUE(q5, 5) ISSUE(q6, 6) ISSUE(q7, 7)
#undef ISSUE
        asm volatile("s_waitcnt vmcnt(0)" ::: "memory");
        unsigned prev = need;
        need = 0u;
#define CHECK(Q, I)                                                       \
        if (prev & (1u << I)) {                                           \
          unsigned bad = ((Q[0] ^ want) | (Q[1] ^ want) | (Q[2] ^ want) | \
                          (Q[3] ^ want)) & 0xFFFFu;                       \
          if (__any(bad != 0u)) need |= (1u << I);                        \
        }
        CHECK(q0, 0) CHECK(q1, 1) CHECK(q2, 2) CHECK(q3, 3)
        CHECK(q4, 4) CHECK(q5, 5) CHECK(q6, 6) CHECK(q7, 7)
#undef CHECK
      } while (need);
      // strip tags -> LDS: row 2i+srow, cols scol4..scol4+3 (one 8B write)
#define STRIP(Q, I)                                                          \
      {                                                                      \
        unsigned lo = __builtin_amdgcn_perm(Q[1], Q[0], 0x07060302u);        \
        unsigned hi = __builtin_amdgcn_perm(Q[3], Q[2], 0x07060302u);        \
        unsigned int* d =                                                    \
            reinterpret_cast<unsigned int*>(&Ald[2 * I + srow][scol4]);      \
        d[0] = lo; d[1] = hi;                                                \
      }
      STRIP(q0, 0) STRIP(q1, 1) STRIP(q2, 2) STRIP(q3, 3)
      STRIP(q4, 4) STRIP(q5, 5) STRIP(q6, 6) STRIP(q7, 7)
#undef STRIP
    }
    __syncthreads();  // B1: h_t staged in LDS

    floatx4 acc = (floatx4){0.f, 0.f, 0.f, 0.f};
    if (t > 0) {
      const int kb = kg * 512 + lk;
#pragma unroll
      for (int q = 0; q < 16; ++q) {
        half8 a = *reinterpret_cast<const half8*>(&Ald[l15][kb + q * 32]);
        acc = __builtin_amdgcn_mfma_f32_16x16x32_f16(a, bfrag[q], acc, 0, 0, 0);
      }
    }
    if (kg == 1) {
#pragma unroll
      for (int i = 0; i < 4; ++i) part[nt][i][l] = acc[i];
    }
    __syncthreads();  // B2: partials ready; protects Ald WAR

    if (kg == 0) {
      unsigned int* outb = hbuf + (size_t)((t + 1) & 1) * 131072 + m * 16384;
#pragma unroll
      for (int i = 0; i < 4; ++i) {
        float pre = acc[i] + part[nt][i][l] + xv[i] + bias_c;
        float xc = fminf(fmaxf(pre, -15.f), 15.f);
        float e = __expf(2.f * xc);
        float dx = (e - 1.f) / (e + 1.f);
        float hn = hown[i] + (dx - hown[i]) * invtau_c;
        hown[i] = hn;
        if (t < SEQ - 1) {
          unsigned short hb = __builtin_bit_cast(unsigned short, (_Float16)hn);
          unsigned word = ((unsigned)hb << 16) | (unsigned)(t + 1);
          __hip_atomic_store(outb + (erow_i + i) * 1024 + ncol, word,
                             __ATOMIC_RELAXED, __HIP_MEMORY_SCOPE_AGENT);
        } else {
          hfinal[(size_t)(erow0 + i) * HIDDEN + ncol] = hn;
        }
      }
    }
  }
}

// ---------------------------------------------------------------------------
// K3: out[B][256] = hfinal @ W_out + b_out
// ---------------------------------------------------------------------------
__global__ __launch_bounds__(256) void out_gemm(
    const float* __restrict__ hfinal, const float* __restrict__ Wout,
    const float* __restrict__ bout, float* __restrict__ out) {
  int b0 = blockIdx.x * 2;
  int o = threadIdx.x;
  float a0 = 0.f, a1 = 0.f;
  for (int k = 0; k < HIDDEN; ++k) {
    float wv = Wout[(size_t)k * OUTPUT + o];
    a0 += hfinal[(size_t)b0 * HIDDEN + k] * wv;
    a1 += hfinal[(size_t)(b0 + 1) * HIDDEN + k] * wv;
  }
  out[(size_t)b0 * OUTPUT + o] = a0 + bout[o];
  out[(size_t)(b0 + 1) * OUTPUT + o] = a1 + bout[o];
}

// ---------------------------------------------------------------------------
extern "C" void kernel_launch(void* const* d_in, const int* in_sizes, int n_in,
                              void* d_out, int out_size, void* d_ws,
                              size_t ws_size, hipStream_t stream) {
  const float* x     = (const float*)d_in[0];
  const float* W_in  = (const float*)d_in[1];
  const float* b_in  = (const float*)d_in[2];
  const float* W_h   = (const float*)d_in[3];
  const float* b_h   = (const float*)d_in[4];
  const float* tau   = (const float*)d_in[5];
  const float* W_out = (const float*)d_in[6];
  const float* b_out = (const float*)d_in[7];
  float* out = (float*)d_out;

  char* ws = (char*)d_ws;
  _Float16* xin = (_Float16*)ws;  ws += (size_t)BATCH * SEQ * HIDDEN * 2;  // 134MB
  _Float16* WinT = (_Float16*)ws; ws += (size_t)HIDDEN * INPUT * 2;        // 1MB
  _Float16* WhT = (_Float16*)ws;  ws += (size_t)HIDDEN * HIDDEN * 2;       // 2MB
  unsigned int* hbuf = (unsigned int*)ws;
  ws += (size_t)2 * BATCH * HIDDEN * 4;                                    // 1MB
  float* hfin = (float*)ws;       ws += (size_t)BATCH * HIDDEN * 4;        // 512KB

  // zero tags (tag 0 is never polled: t=0 skips the MFMA since h_0 = 0)
  hipMemsetAsync(hbuf, 0, (size_t)2 * BATCH * HIDDEN * 4, stream);

  transpose_f32_to_f16<<<dim3(INPUT / 32, HIDDEN / 32), 256, 0, stream>>>(
      W_in, WinT, INPUT, HIDDEN);
  transpose_f32_to_f16<<<dim3(HIDDEN / 32, HIDDEN / 32), 256, 0, stream>>>(
      W_h, WhT, HIDDEN, HIDDEN);

  xin_gemm<<<(BATCH * SEQ / 64) * (HIDDEN / 64), 256, 0, stream>>>(x, WinT, xin);

  liquid_scan<<<128, 512, 0, stream>>>(xin, WhT, b_in, b_h, tau, hbuf, hfin);

  out_gemm<<<BATCH / 2, OUTPUT, 0, stream>>>(hfin, W_out, b_out, out);
}